// Round 8
// baseline (26.160 us; speedup 1.0000x reference)
//
#include <hip/hip_runtime.h>
#include <stdint.h>

#define THREADS 1024
#define NWAVE 16
#define NB 1024      // fallback histogram buckets over [0,1)
#define NH 16        // per-wave partial histograms
#define CAP 256      // candidate buffer capacity
#define WANT 128     // fallback: target candidates per batch
#define MAXKEEP 128  // kept-list capacity (maxout<=100 on bench)
#define T0 0.9765625f  // 1 - 3/128, exact float; bucket(T0)=1000 (NB=1024)

__device__ __forceinline__ float fence(float x) {
  asm("" : "+v"(x));  // block fp-contract; match jnp rounding exactly
  return x;
}

__device__ __forceinline__ uint32_t rdlane32(uint32_t v, int l) {
  return (uint32_t)__builtin_amdgcn_readlane((int)v, l);
}

// ---------------- fallback-only machinery (proven R5-R7) ----------------
#define REGSTAGE(KK, JV)                                              \
  do {                                                                \
    _Pragma("unroll") for (int v = 0; v < 4; ++v) {                   \
      if ((v & (JV)) == 0) {                                          \
        uint64_t a = k[v], b = k[v | (JV)];                           \
        bool descRun = (((v * 64) & (KK)) == 0);                      \
        uint64_t mx = a > b ? a : b, mn = a > b ? b : a;              \
        k[v] = descRun ? mx : mn;                                     \
        k[v | (JV)] = descRun ? mn : mx;                              \
      }                                                               \
    }                                                                 \
  } while (0)

#define SHSTAGE(KK, J)                                                \
  do {                                                                \
    _Pragma("unroll") for (int v = 0; v < 4; ++v) {                   \
      uint64_t a = k[v];                                              \
      uint64_t b = __shfl_xor(a, (J), 64);                            \
      int e = v * 64 + lane;                                          \
      bool descRun = ((e & (KK)) == 0);                               \
      bool lower = ((lane & (J)) == 0);                               \
      uint64_t mx = a > b ? a : b, mn = a > b ? b : a;                \
      k[v] = (descRun == lower) ? mx : mn;                            \
    }                                                                 \
  } while (0)

#define SH32TO1(KK)                                                   \
  SHSTAGE(KK, 32); SHSTAGE(KK, 16); SHSTAGE(KK, 8);                   \
  SHSTAGE(KK, 4); SHSTAGE(KK, 2); SHSTAGE(KK, 1)

__device__ __forceinline__ void sort256(int lane, int cnt,
                                        const uint64_t* cand, uint64_t k[4]) {
#pragma unroll
  for (int v = 0; v < 4; ++v) {
    int e = v * 64 + lane;
    k[v] = (e < cnt) ? cand[e] : 0ull;  // 0 sorts to the end
  }
  SHSTAGE(2, 1);
  SHSTAGE(4, 2); SHSTAGE(4, 1);
  SHSTAGE(8, 4); SHSTAGE(8, 2); SHSTAGE(8, 1);
  SHSTAGE(16, 8); SHSTAGE(16, 4); SHSTAGE(16, 2); SHSTAGE(16, 1);
  SHSTAGE(32, 16); SHSTAGE(32, 8); SHSTAGE(32, 4); SHSTAGE(32, 2);
  SHSTAGE(32, 1);
  SHSTAGE(64, 32); SHSTAGE(64, 16); SHSTAGE(64, 8); SHSTAGE(64, 4);
  SHSTAGE(64, 2); SHSTAGE(64, 1);
  REGSTAGE(128, 1); SH32TO1(128);
  REGSTAGE(256, 2); REGSTAGE(256, 1); SH32TO1(256);
}

__device__ __forceinline__ int greedy4(int lane, int cnt, int kept, int maxout,
                                       float thr, const uint64_t k[4],
                                       const float4* candbox, float4* cbox,
                                       float* careaS, float4* kbox,
                                       float* kareaS, int* kidxS) {
#pragma unroll
  for (int c = 0; c < 4; ++c) {
    if (c * 64 < cnt && kept < maxout) {
      uint64_t key = k[c];
      bool valid = (c * 64 + lane) < cnt;
      int slot = valid ? (int)(key & 0x3FFFF) : 0;
      int idx = valid ? (8192 - (int)((key >> 18) & 0x3FFF)) : 0;
      float4 bb = candbox[slot];
      float x1 = bb.x, y1 = bb.y, x2 = bb.z, y2 = bb.w;
      float areaj = fence((x2 - x1) * (y2 - y1));
      const int kbase = kept;

      bool supp = !valid;
#pragma unroll 4
      for (int t = 0; t < kbase; ++t) {
        float4 kb = kbox[t];
        float ka = kareaS[t];
        float iw = fmaxf(fminf(kb.z, x2) - fmaxf(kb.x, x1), 0.0f);
        float ih = fmaxf(fminf(kb.w, y2) - fmaxf(kb.y, y1), 0.0f);
        float inter = fence(iw * ih);
        float denom = (ka + areaj) - inter;
        if (inter / denom > thr) supp = true;
      }

      cbox[lane] = bb;
      careaS[lane] = areaj;
      uint64_t row = 0;
#pragma unroll 8
      for (int j = 0; j < 64; ++j) {
        float4 ib = cbox[j];
        float ia = careaS[j];
        float iw = fmaxf(fminf(ib.z, x2) - fmaxf(ib.x, x1), 0.0f);
        float ih = fmaxf(fminf(ib.w, y2) - fmaxf(ib.y, y1), 0.0f);
        float inter = fence(iw * ih);
        float denom = (ia + areaj) - inter;
        if (inter / denom > thr) row |= (1ull << j);
      }

      const uint64_t self = 1ull << lane;
      uint64_t alive = __ballot(valid && !supp);
      uint64_t rowNS = row & ~self;
      uint64_t conflict = __ballot(valid && !supp && ((rowNS & alive) != 0));
      uint64_t keepm;
      const int budget = maxout - kept;
      if (conflict == 0) {
        int na = __popcll((unsigned long long)alive);
        if (na <= budget) {
          keepm = alive;
          kept += na;
        } else {
          int lo = 0;
#pragma unroll
          for (int s = 32; s >= 1; s >>= 1) {
            int t2 = lo + s;
            uint64_t mk = (t2 >= 64) ? ~0ull : ((1ull << t2) - 1ull);
            if (__popcll((unsigned long long)(alive & mk)) < budget) lo = t2;
          }
          uint64_t mk2 = ((lo + 1) >= 64) ? ~0ull : ((1ull << (lo + 1)) - 1ull);
          keepm = alive & mk2;
          kept += budget;
        }
      } else {
        uint32_t rlo = (uint32_t)row, rhi = (uint32_t)(row >> 32);
        keepm = 0;
        while (alive != 0 && kept < maxout) {
          int b2 = __ffsll((unsigned long long)alive) - 1;
          keepm |= (1ull << b2);
          kept++;
          uint64_t rb = ((uint64_t)rdlane32(rhi, b2) << 32) |
                        (uint64_t)rdlane32(rlo, b2);
          alive &= ~rb;
          alive &= ~(1ull << b2);
        }
      }
      if ((keepm >> lane) & 1) {
        int rank = __popcll((unsigned long long)(keepm & (self - 1ull)));
        kbox[kbase + rank] = bb;
        kareaS[kbase + rank] = areaj;
        kidxS[kbase + rank] = idx;
      }
    }
  }
  return kept;
}

// ---------------------------------------------------------------------------
__global__ __launch_bounds__(THREADS) void nms_rank4_kernel(
    const float* __restrict__ boxes, const float* __restrict__ scores, int n,
    const float* __restrict__ thr_p, const int* __restrict__ maxout_p,
    int* __restrict__ out, int out_size) {
  __shared__ __align__(16) uint32_t hist[NH][NB];  // 64 KB (fallback only)
  __shared__ uint32_t wcnt[NWAVE];
  __shared__ uint64_t cand[CAP];     // compacted keys (slot order)
  __shared__ float4 candbox[CAP];    // fallback: coords by slot
  __shared__ float4 candboxR[CAP];   // fast: coords by RANK
  __shared__ float2 cxyR[CAP];       // fast: centers by RANK (prefilter)
  __shared__ float areaR[CAP];       // fast: areas by RANK
  __shared__ int sidxR[CAP];         // fast: original index by RANK
  __shared__ uint64_t adjm[CAP][4];  // fast: adjacency rows (rank space)
  __shared__ float4 cbox[64];        // fallback greedy4 scratch
  __shared__ float careaS[64];
  __shared__ float4 kbox[MAXKEEP];
  __shared__ float kareaS[MAXKEEP];
  __shared__ int kidxS[MAXKEEP];
  __shared__ int s_cut, s_hi, s_kept, s_done;

  const int tid = threadIdx.x;
  const int lane = tid & 63;
  const int wid = tid >> 6;

  const float thr = *thr_p;
  int maxout = *maxout_p;
  if (maxout > out_size) maxout = out_size;
  if (maxout > MAXKEEP) maxout = MAXKEEP;

  // ---- load this thread's 8 scores into registers (cold HBM, 16-wave TLP) --
  float sc[8];
  const int base = tid * 8;
  if (base + 7 < n) {
    const float4* sp = reinterpret_cast<const float4*>(scores) + 2 * tid;
    float4 a = sp[0], b2 = sp[1];
    sc[0] = a.x; sc[1] = a.y; sc[2] = a.z; sc[3] = a.w;
    sc[4] = b2.x; sc[5] = b2.y; sc[6] = b2.z; sc[7] = b2.w;
  } else {
#pragma unroll
    for (int r = 0; r < 8; ++r)
      sc[r] = (base + r < n) ? scores[base + r] : -1.0f;
  }

  // ---- fast path: count survivors of fixed threshold T0 ----
  int wtot = 0;
#pragma unroll
  for (int r = 0; r < 8; ++r) {
    bool pred = (base + r < n) && (sc[r] >= T0);
    wtot += __popcll((unsigned long long)__ballot(pred));
  }
  if (lane == 0) wcnt[wid] = (uint32_t)wtot;
  __syncthreads();
  int cbase = 0, total = 0;
#pragma unroll
  for (int w = 0; w < NWAVE; ++w) {
    int c = (int)wcnt[w];
    if (w < wid) cbase += c;
    total += c;
  }

  const bool fast_ok = (total <= CAP);  // block-uniform
  bool done = false;
  if (fast_ok) {
    // ---- compact keys (atomic-free, deterministic) + zero-pad ----
    int run = cbase;
#pragma unroll
    for (int r = 0; r < 8; ++r) {
      int idx = base + r;
      bool pred = (idx < n) && (sc[r] >= T0);
      uint64_t m = __ballot(pred);
      if (pred) {
        int pos = run + __popcll((unsigned long long)(m & ((1ull << lane) - 1)));
        // key: [63:32]=score bits, [31:18]=8192-idx (stable tie; >0 so no
        // real key equals the 0 pad), [17:0]=slot (order-neutral).
        cand[pos] = ((uint64_t)__float_as_uint(sc[r]) << 32) |
                    ((uint64_t)(8192 - idx) << 18) | (uint64_t)pos;
      }
      run += __popcll((unsigned long long)m);
    }
    if (tid >= total && tid < CAP) cand[tid] = 0;  // pad sorts last
    __syncthreads();  // A: keys visible

    const int cnt = total;
    const int c = tid >> 2;  // candidate owned by this 4-thread team
    const int h = tid & 3;   // this thread handles cols q == h (mod 4)

    uint64_t mykey = 0;
    float4 bb;
    int myidx = 0;
    if (c < cnt) {
      mykey = cand[c];
      if (h == 0) {  // issue cold box load early; hides under rank loop
        myidx = 8192 - (int)((mykey >> 18) & 0x3FFF);
        bb = *reinterpret_cast<const float4*>(boxes + 4 * (size_t)myidx);
      }
    }

    // ---- rank-by-count: fixed-64 fully-unrolled (pipelined LDS reads) ----
    int rc = 0;
    {
      int r0 = 0, r1 = 0;
#pragma unroll
      for (int i = 0; i < CAP / 8; ++i) {  // two streams: more ILP
        uint64_t ka = cand[8 * i + h];
        uint64_t kb = cand[8 * i + 4 + h];
        r0 += (ka > mykey) ? 1 : 0;
        r1 += (kb > mykey) ? 1 : 0;
      }
      rc = r0 + r1;  // pad keys are 0: never > any real key
    }
    rc += __shfl_xor(rc, 1, 64);
    rc += __shfl_xor(rc, 2, 64);  // all 4 team threads hold full rank
    if (c < cnt && h == 0) {
      candboxR[rc] = bb;
      sidxR[rc] = myidx;
      cxyR[rc] = make_float2((bb.x + bb.z) * 0.5f, (bb.y + bb.w) * 0.5f);
      areaR[rc] = fence((bb.z - bb.x) * (bb.w - bb.y));
    }
    __syncthreads();  // B: rank-ordered boxes visible

    // ---- adjacency word h of row c: fixed-64 unrolled + center prefilter ---
    // IoU(p,q) > thr >= 0 requires geometric overlap => |dcx|,|dcy| <= 100
    // (wh <= 100 in this data is NOT assumed: bound uses the boxes' own
    //  half-width sums; we use a conservative radius from the tier's boxes).
    if (c < cnt) {
      float4 mb = candboxR[c];
      float marea = areaR[c];
      float mcx = (mb.x + mb.z) * 0.5f;
      float mcy = (mb.y + mb.w) * 0.5f;
      float mrx = (mb.z - mb.x) * 0.5f;  // my half-extents
      float mry = (mb.w - mb.y) * 0.5f;
      const bool use_pf = (thr >= 0.0f);  // thr<0: zero-overlap can suppress
      uint64_t acc = 0;
      const int qbase = h << 6;
#pragma unroll
      for (int j = 0; j < 64; ++j) {
        const int q = qbase + j;
        if (q < cnt) {
          float2 cq = cxyR[q];
          // overlap requires |dc| < (half-extent sums); radius bound:
          // rx_q <= 64 px is NOT known, so use box-exact test via extents
          // stored implicitly: |dcx| < mrx + rx_q. rx_q unknown here without
          // loading the box; use a 2-stage test: cheap center distance vs
          // (mrx + 64) would be unsound. Instead load is gated by a sound
          // coarse test: |dcx| < mrx + 50.5 fails only if rx_q <= 50.5 --
          // not guaranteed. So: sound test = |dcx| < mrx + RQMAX where
          // RQMAX bounds all candidate half-widths. Compute RQMAX=inf when
          // unknown? To stay exact we fall back to the full IoU whenever
          // the cheap test passes OR rx_q could exceed RQMAX. Simplest
          // SOUND choice: skip prefilter unless all boxes' half-extents
          // are <= 50.5 (true for this data: wh in (1,101] => half <= 50.5).
          // That property is checked per-candidate at rank time? Not stored.
          // => gate on box-exact overlap instead: load cq plus extents.
          float2 eq = make_float2(candboxR[q].z - candboxR[q].x,
                                  candboxR[q].w - candboxR[q].y);
          float dx = fabsf(cq.x - mcx);
          float dy = fabsf(cq.y - mcy);
          bool close = !use_pf | ((dx * 2.0f <= (mrx * 2.0f + eq.x) * 1.0000002f) &
                                  (dy * 2.0f <= (mry * 2.0f + eq.y) * 1.0000002f));
          if (close) {
            float4 qb = candboxR[q];
            float qarea = areaR[q];
            float iw = fmaxf(fminf(qb.z, mb.z) - fmaxf(qb.x, mb.x), 0.0f);
            float ih = fmaxf(fminf(qb.w, mb.w) - fmaxf(qb.y, mb.y), 0.0f);
            float inter = fence(iw * ih);
            float denom = (qarea + marea) - inter;
            if (inter / denom > thr) acc |= (1ull << j);
          }
        }
      }
      adjm[c][h] = acc;
    }
    __syncthreads();  // C: adjacency visible

    // ---- wave 0: mask-only greedy ----
    if (wid == 0) {
      uint64_t km[4] = {0, 0, 0, 0};
      int kept = 0;
#pragma unroll
      for (int cch = 0; cch < 4; ++cch) {
        if (cch * 64 < cnt && kept < maxout) {
          const int p = cch * 64 + lane;
          const bool valid = p < cnt;
          uint64_t r0 = 0, r1 = 0, r2 = 0, r3 = 0;
          if (valid) {
            r0 = adjm[p][0]; r1 = adjm[p][1];
            r2 = adjm[p][2]; r3 = adjm[p][3];
          }
          const uint64_t self = 1ull << lane;
          bool supp = !valid ||
                      (((r0 & km[0]) | (r1 & km[1]) | (r2 & km[2]) |
                        (r3 & km[3])) != 0);
          uint64_t alive = __ballot(valid && !supp);
          uint64_t wc = (cch == 0) ? r0 : (cch == 1) ? r1 : (cch == 2) ? r2 : r3;
          uint64_t conflict =
              __ballot(valid && !supp && ((wc & ~self & alive) != 0));
          uint64_t keepm;
          const int kbase = kept;
          const int budget = maxout - kept;
          if (conflict == 0) {
            int na = __popcll((unsigned long long)alive);
            if (na <= budget) {
              keepm = alive;
              kept += na;
            } else {
              int lo = 0;
#pragma unroll
              for (int s = 32; s >= 1; s >>= 1) {
                int t2 = lo + s;
                uint64_t mk = (t2 >= 64) ? ~0ull : ((1ull << t2) - 1ull);
                if (__popcll((unsigned long long)(alive & mk)) < budget) lo = t2;
              }
              uint64_t mk2 =
                  ((lo + 1) >= 64) ? ~0ull : ((1ull << (lo + 1)) - 1ull);
              keepm = alive & mk2;
              kept += budget;
            }
          } else {
            uint32_t rlo = (uint32_t)wc, rhi = (uint32_t)(wc >> 32);
            keepm = 0;
            while (alive != 0 && kept < maxout) {
              int b2 = __ffsll((unsigned long long)alive) - 1;
              keepm |= (1ull << b2);
              kept++;
              uint64_t rb = ((uint64_t)rdlane32(rhi, b2) << 32) |
                            (uint64_t)rdlane32(rlo, b2);
              alive &= ~rb;
              alive &= ~(1ull << b2);  // safety: degenerate box self-IoU NaN
            }
          }
          km[cch] = keepm;
          if ((keepm >> lane) & 1) {
            int rk = kbase +
                     __popcll((unsigned long long)(keepm & (self - 1ull)));
            kidxS[rk] = sidxR[p];
            float4 pb = candboxR[p];  // keep fallback continuation exact
            kbox[rk] = pb;
            kareaS[rk] = fence((pb.z - pb.x) * (pb.w - pb.y));
          }
        }
      }
      if (lane == 0) {
        s_kept = kept;
        s_done = (kept >= maxout) ? 1 : 0;
      }
    }
    __syncthreads();  // D
    done = (s_done != 0);
  }

  if (!done) {
    // ---- fallback: exact histogram-batched path (not taken on bench) ----
    {
      uint32_t* hh = &hist[0][0];
      for (int i = tid; i < NH * NB; i += THREADS) hh[i] = 0;
    }
    if (tid == 0) {
      s_hi = fast_ok ? 999 : (NB - 1);  // bucket(T0)-1 when fast tier consumed
      if (!fast_ok) s_kept = 0;
      s_done = 0;
    }
    __syncthreads();
    const int hicap = fast_ok ? 999 : (NB - 1);
    {
      uint32_t* myh = hist[wid];
#pragma unroll
      for (int r = 0; r < 8; ++r) {
        if (base + r < n) {
          int b = (int)(sc[r] * (float)NB);
          b = b < 0 ? 0 : (b > NB - 1 ? NB - 1 : b);
          if (b <= hicap) atomicAdd(&myh[b], 1u);
        }
      }
    }
    __syncthreads();
    for (int i = tid; i < NB; i += THREADS) {
      uint32_t s = 0;
#pragma unroll
      for (int hh = 0; hh < NH; ++hh) s += hist[hh][i];
      hist[0][i] = s;
    }
    __syncthreads();

    while (true) {
      if (wid == 0) {
        uint32_t csum = 0;
        const uint4* hp = reinterpret_cast<const uint4*>(&hist[0][lane * 16]);
#pragma unroll
        for (int i = 0; i < 4; ++i) {
          uint4 h4 = hp[i];
          csum += h4.x + h4.y + h4.z + h4.w;
        }
        uint32_t suf = csum;
#pragma unroll
        for (int off = 1; off < 64; off <<= 1) {
          uint32_t v = __shfl_down(suf, off, 64);
          suf += (lane + off < 64) ? v : 0u;
        }
        uint64_t mask = __ballot(suf >= (uint32_t)WANT);
        int cut;
        if (mask == 0) {
          cut = 0;
        } else {
          int cstar = 63 - __builtin_clzll((unsigned long long)mask);
          int src = cstar + 1 < 63 ? cstar + 1 : 63;
          uint32_t above_raw = __shfl(suf, src, 64);
          uint32_t above = (cstar < 63) ? above_raw : 0u;
          uint32_t h2 = (lane < 16) ? hist[0][cstar * 16 + lane] : 0u;
          uint32_t suf2 = h2;
#pragma unroll
          for (int off = 1; off < 64; off <<= 1) {
            uint32_t v = __shfl_down(suf2, off, 64);
            suf2 += (lane + off < 64) ? v : 0u;
          }
          uint64_t mask2 =
              __ballot((lane < 16) && (above + suf2 >= (uint32_t)WANT));
          int b2 = 63 - __builtin_clzll((unsigned long long)mask2);
          cut = cstar * 16 + b2;
        }
        if (lane == 0) s_cut = cut;
      }
      __syncthreads();
      const int cut = s_cut;
      const int hi = s_hi;
      const float lo_f =
          (cut == 0) ? -__builtin_huge_valf() : (float)cut / (float)NB;
      const bool top_open = (hi == NB - 1);
      const float up_f = (float)(hi + 1) / (float)NB;

      int wt = 0;
#pragma unroll
      for (int r = 0; r < 8; ++r) {
        int idx = base + r;
        bool pred = (idx < n) && (sc[r] >= lo_f) && (top_open || sc[r] < up_f);
        wt += __popcll((unsigned long long)__ballot(pred));
      }
      if (lane == 0) wcnt[wid] = (uint32_t)wt;
      __syncthreads();
      int cb2 = 0, tot2 = 0;
#pragma unroll
      for (int w = 0; w < NWAVE; ++w) {
        int cc = (int)wcnt[w];
        if (w < wid) cb2 += cc;
        tot2 += cc;
      }
      {
        int run2 = cb2;
#pragma unroll
        for (int r = 0; r < 8; ++r) {
          int idx = base + r;
          bool pred =
              (idx < n) && (sc[r] >= lo_f) && (top_open || sc[r] < up_f);
          uint64_t m = __ballot(pred);
          if (pred) {
            int pos =
                run2 + __popcll((unsigned long long)(m & ((1ull << lane) - 1)));
            if (pos < CAP) {
              cand[pos] = ((uint64_t)__float_as_uint(sc[r]) << 32) |
                          ((uint64_t)(8192 - idx) << 18) | (uint64_t)pos;
              candbox[pos] =
                  *reinterpret_cast<const float4*>(boxes + 4 * (size_t)idx);
            }
          }
          run2 += __popcll((unsigned long long)m);
        }
      }
      __syncthreads();
      int cnt2 = tot2 > CAP ? CAP : tot2;
      if (wid == 0) {
        uint64_t k2[4];
        sort256(lane, cnt2, cand, k2);
        int kept = greedy4(lane, cnt2, s_kept, maxout, thr, k2, candbox, cbox,
                           careaS, kbox, kareaS, kidxS);
        if (lane == 0) {
          s_kept = kept;
          s_hi = cut - 1;
          s_done = (kept >= maxout || cut == 0) ? 1 : 0;
        }
      }
      __syncthreads();
      if (s_done) break;
      for (int b = cut + tid; b <= hi; b += THREADS) hist[0][b] = 0;
      __syncthreads();
    }
  }

  // output (harness never re-poisons: write every element every call)
  const int keptf = s_kept;
  for (int i = tid; i < out_size; i += THREADS)
    out[i] = (i < keptf) ? kidxS[i] : -1;
}

extern "C" void kernel_launch(void* const* d_in, const int* in_sizes, int n_in,
                              void* d_out, int out_size, void* d_ws,
                              size_t ws_size, hipStream_t stream) {
  const float* boxes = (const float*)d_in[0];
  const float* scores = (const float*)d_in[1];
  const float* thr = (const float*)d_in[2];
  const int* maxout = (const int*)d_in[3];
  int n = in_sizes[1];
  int* out = (int*)d_out;

  hipLaunchKernelGGL(nms_rank4_kernel, dim3(1), dim3(THREADS), 0, stream,
                     boxes, scores, n, thr, maxout, out, out_size);
}

// Round 9
// 23.253 us; speedup vs baseline: 1.1250x; 1.1250x over previous
//
#include <hip/hip_runtime.h>
#include <stdint.h>

#define THREADS 1024
#define NWAVE 16
#define NB 1024      // fallback histogram buckets over [0,1)
#define NH 16        // per-wave partial histograms
#define CAP 256      // candidate buffer capacity
#define WANT 128     // fallback: target candidates per batch
#define MAXKEEP 128  // kept-list capacity (maxout<=100 on bench)
#define T0 0.9765625f  // 1000/1024, exact float; bucket(T0)=1000 (NB=1024)

__device__ __forceinline__ float fence(float x) {
  asm("" : "+v"(x));  // block fp-contract; match jnp rounding exactly
  return x;
}

__device__ __forceinline__ uint32_t rdlane32(uint32_t v, int l) {
  return (uint32_t)__builtin_amdgcn_readlane((int)v, l);
}

// ---------------- fallback-only machinery (proven R5-R8) ----------------
#define REGSTAGE(KK, JV)                                              \
  do {                                                                \
    _Pragma("unroll") for (int v = 0; v < 4; ++v) {                   \
      if ((v & (JV)) == 0) {                                          \
        uint64_t a = k[v], b = k[v | (JV)];                           \
        bool descRun = (((v * 64) & (KK)) == 0);                      \
        uint64_t mx = a > b ? a : b, mn = a > b ? b : a;              \
        k[v] = descRun ? mx : mn;                                     \
        k[v | (JV)] = descRun ? mn : mx;                              \
      }                                                               \
    }                                                                 \
  } while (0)

#define SHSTAGE(KK, J)                                                \
  do {                                                                \
    _Pragma("unroll") for (int v = 0; v < 4; ++v) {                   \
      uint64_t a = k[v];                                              \
      uint64_t b = __shfl_xor(a, (J), 64);                            \
      int e = v * 64 + lane;                                          \
      bool descRun = ((e & (KK)) == 0);                               \
      bool lower = ((lane & (J)) == 0);                               \
      uint64_t mx = a > b ? a : b, mn = a > b ? b : a;                \
      k[v] = (descRun == lower) ? mx : mn;                            \
    }                                                                 \
  } while (0)

#define SH32TO1(KK)                                                   \
  SHSTAGE(KK, 32); SHSTAGE(KK, 16); SHSTAGE(KK, 8);                   \
  SHSTAGE(KK, 4); SHSTAGE(KK, 2); SHSTAGE(KK, 1)

__device__ __forceinline__ void sort256(int lane, int cnt,
                                        const uint64_t* cand, uint64_t k[4]) {
#pragma unroll
  for (int v = 0; v < 4; ++v) {
    int e = v * 64 + lane;
    k[v] = (e < cnt) ? cand[e] : 0ull;  // 0 sorts to the end
  }
  SHSTAGE(2, 1);
  SHSTAGE(4, 2); SHSTAGE(4, 1);
  SHSTAGE(8, 4); SHSTAGE(8, 2); SHSTAGE(8, 1);
  SHSTAGE(16, 8); SHSTAGE(16, 4); SHSTAGE(16, 2); SHSTAGE(16, 1);
  SHSTAGE(32, 16); SHSTAGE(32, 8); SHSTAGE(32, 4); SHSTAGE(32, 2);
  SHSTAGE(32, 1);
  SHSTAGE(64, 32); SHSTAGE(64, 16); SHSTAGE(64, 8); SHSTAGE(64, 4);
  SHSTAGE(64, 2); SHSTAGE(64, 1);
  REGSTAGE(128, 1); SH32TO1(128);
  REGSTAGE(256, 2); REGSTAGE(256, 1); SH32TO1(256);
}

__device__ __forceinline__ int greedy4(int lane, int cnt, int kept, int maxout,
                                       float thr, const uint64_t k[4],
                                       const float4* candbox, float4* cbox,
                                       float* careaS, float4* kbox,
                                       float* kareaS, int* kidxS) {
#pragma unroll
  for (int c = 0; c < 4; ++c) {
    if (c * 64 < cnt && kept < maxout) {
      uint64_t key = k[c];
      bool valid = (c * 64 + lane) < cnt;
      int slot = valid ? (int)(key & 0x3FFFF) : 0;
      int idx = valid ? (8192 - (int)((key >> 18) & 0x3FFF)) : 0;
      float4 bb = candbox[slot];
      float x1 = bb.x, y1 = bb.y, x2 = bb.z, y2 = bb.w;
      float areaj = fence((x2 - x1) * (y2 - y1));
      const int kbase = kept;

      bool supp = !valid;
#pragma unroll 4
      for (int t = 0; t < kbase; ++t) {
        float4 kb = kbox[t];
        float ka = kareaS[t];
        float iw = fmaxf(fminf(kb.z, x2) - fmaxf(kb.x, x1), 0.0f);
        float ih = fmaxf(fminf(kb.w, y2) - fmaxf(kb.y, y1), 0.0f);
        float inter = fence(iw * ih);
        float denom = (ka + areaj) - inter;
        if (inter / denom > thr) supp = true;
      }

      cbox[lane] = bb;
      careaS[lane] = areaj;
      uint64_t row = 0;
#pragma unroll 8
      for (int j = 0; j < 64; ++j) {
        float4 ib = cbox[j];
        float ia = careaS[j];
        float iw = fmaxf(fminf(ib.z, x2) - fmaxf(ib.x, x1), 0.0f);
        float ih = fmaxf(fminf(ib.w, y2) - fmaxf(ib.y, y1), 0.0f);
        float inter = fence(iw * ih);
        float denom = (ia + areaj) - inter;
        if (inter / denom > thr) row |= (1ull << j);
      }

      const uint64_t self = 1ull << lane;
      uint64_t alive = __ballot(valid && !supp);
      uint64_t rowNS = row & ~self;
      uint64_t conflict = __ballot(valid && !supp && ((rowNS & alive) != 0));
      uint64_t keepm;
      const int budget = maxout - kept;
      if (conflict == 0) {
        int na = __popcll((unsigned long long)alive);
        if (na <= budget) {
          keepm = alive;
          kept += na;
        } else {
          int lo = 0;
#pragma unroll
          for (int s = 32; s >= 1; s >>= 1) {
            int t2 = lo + s;
            uint64_t mk = (t2 >= 64) ? ~0ull : ((1ull << t2) - 1ull);
            if (__popcll((unsigned long long)(alive & mk)) < budget) lo = t2;
          }
          uint64_t mk2 = ((lo + 1) >= 64) ? ~0ull : ((1ull << (lo + 1)) - 1ull);
          keepm = alive & mk2;
          kept += budget;
        }
      } else {
        uint32_t rlo = (uint32_t)row, rhi = (uint32_t)(row >> 32);
        keepm = 0;
        while (alive != 0 && kept < maxout) {
          int b2 = __ffsll((unsigned long long)alive) - 1;
          keepm |= (1ull << b2);
          kept++;
          uint64_t rb = ((uint64_t)rdlane32(rhi, b2) << 32) |
                        (uint64_t)rdlane32(rlo, b2);
          alive &= ~rb;
          alive &= ~(1ull << b2);
        }
      }
      if ((keepm >> lane) & 1) {
        int rank = __popcll((unsigned long long)(keepm & (self - 1ull)));
        kbox[kbase + rank] = bb;
        kareaS[kbase + rank] = areaj;
        kidxS[kbase + rank] = idx;
      }
    }
  }
  return kept;
}

// ---------------------------------------------------------------------------
__global__ __launch_bounds__(THREADS) void nms_rank5_kernel(
    const float* __restrict__ boxes, const float* __restrict__ scores, int n,
    const float* __restrict__ thr_p, const int* __restrict__ maxout_p,
    int* __restrict__ out, int out_size) {
  __shared__ __align__(16) uint32_t hist[NH][NB];  // 64 KB (fallback only)
  __shared__ uint32_t wcnt[NWAVE];
  __shared__ uint64_t cand[CAP];     // compacted keys (slot order)
  __shared__ float4 candbox[CAP];    // fallback: coords by slot
  __shared__ float4 candboxR[CAP];   // fast: coords by RANK
  __shared__ float2 cxyR[CAP];       // fast: centers by RANK (prefilter)
  __shared__ float areaR[CAP];       // fast: areas by RANK
  __shared__ int sidxR[CAP];         // fast: original index by RANK
  __shared__ uint64_t adjm[CAP][4];  // fast: adjacency rows (rank space)
  __shared__ float4 cbox[64];        // fallback greedy4 scratch
  __shared__ float careaS[64];
  __shared__ float4 kbox[MAXKEEP];
  __shared__ float kareaS[MAXKEEP];
  __shared__ int kidxS[MAXKEEP];
  __shared__ int s_cut, s_hi, s_kept, s_done, s_rmax_i;

  const int tid = threadIdx.x;
  const int lane = tid & 63;
  const int wid = tid >> 6;

  const float thr = *thr_p;
  int maxout = *maxout_p;
  if (maxout > out_size) maxout = out_size;
  if (maxout > MAXKEEP) maxout = MAXKEEP;

  // ---- load this thread's 8 scores into registers (cold HBM, 16-wave TLP) --
  float sc[8];
  const int base = tid * 8;
  if (base + 7 < n) {
    const float4* sp = reinterpret_cast<const float4*>(scores) + 2 * tid;
    float4 a = sp[0], b2 = sp[1];
    sc[0] = a.x; sc[1] = a.y; sc[2] = a.z; sc[3] = a.w;
    sc[4] = b2.x; sc[5] = b2.y; sc[6] = b2.z; sc[7] = b2.w;
  } else {
#pragma unroll
    for (int r = 0; r < 8; ++r)
      sc[r] = (base + r < n) ? scores[base + r] : -1.0f;
  }

  // ---- fast path: count survivors of fixed threshold T0 ----
  int wtot = 0;
#pragma unroll
  for (int r = 0; r < 8; ++r) {
    bool pred = (base + r < n) && (sc[r] >= T0);
    wtot += __popcll((unsigned long long)__ballot(pred));
  }
  if (lane == 0) wcnt[wid] = (uint32_t)wtot;
  if (tid == 0) s_rmax_i = 0;
  __syncthreads();
  int cbase = 0, total = 0;
#pragma unroll
  for (int w = 0; w < NWAVE; ++w) {
    int c = (int)wcnt[w];
    if (w < wid) cbase += c;
    total += c;
  }

  const bool fast_ok = (total <= CAP);  // block-uniform
  bool done = false;
  if (fast_ok) {
    // ---- compact keys (atomic-free, deterministic) + zero-pad ----
    int run = cbase;
#pragma unroll
    for (int r = 0; r < 8; ++r) {
      int idx = base + r;
      bool pred = (idx < n) && (sc[r] >= T0);
      uint64_t m = __ballot(pred);
      if (pred) {
        int pos = run + __popcll((unsigned long long)(m & ((1ull << lane) - 1)));
        // key: [63:32]=score bits, [31:18]=8192-idx (stable tie; >0 so no
        // real key equals the 0 pad), [17:0]=slot (order-neutral).
        cand[pos] = ((uint64_t)__float_as_uint(sc[r]) << 32) |
                    ((uint64_t)(8192 - idx) << 18) | (uint64_t)pos;
      }
      run += __popcll((unsigned long long)m);
    }
    if (tid >= total && tid < CAP) cand[tid] = 0;  // pad sorts last
    __syncthreads();  // A: keys visible

    const int cnt = total;
    const int c = tid >> 2;  // candidate owned by this 4-thread team
    const int h = tid & 3;   // this thread handles cols q == h (mod 4)

    uint64_t mykey = 0;
    float4 bb;
    int myidx = 0;
    if (c < cnt) {
      mykey = cand[c];
      if (h == 0) {  // issue cold box load early; hides under rank loop
        myidx = 8192 - (int)((mykey >> 18) & 0x3FFF);
        bb = *reinterpret_cast<const float4*>(boxes + 4 * (size_t)myidx);
      }
    }

    // ---- rank-by-count: fixed-64 fully-unrolled (pipelined LDS reads) ----
    int rc = 0;
    {
      int r0 = 0, r1 = 0;
#pragma unroll
      for (int i = 0; i < CAP / 8; ++i) {  // two streams: more ILP
        uint64_t ka = cand[8 * i + h];
        uint64_t kb = cand[8 * i + 4 + h];
        r0 += (ka > mykey) ? 1 : 0;
        r1 += (kb > mykey) ? 1 : 0;
      }
      rc = r0 + r1;  // pad keys are 0: never > any real key
    }
    rc += __shfl_xor(rc, 1, 64);
    rc += __shfl_xor(rc, 2, 64);  // all 4 team threads hold full rank

    // block max half-extent (prefilter radius bound; exact upper bound)
    float rm = 0.0f;
    if (c < cnt && h == 0)
      rm = fmaxf((bb.z - bb.x) * 0.5f, (bb.w - bb.y) * 0.5f);
#pragma unroll
    for (int off = 1; off < 64; off <<= 1)
      rm = fmaxf(rm, __shfl_xor(rm, off, 64));
    if (lane == 0) atomicMax(&s_rmax_i, __float_as_int(rm));

    if (c < cnt && h == 0) {
      candboxR[rc] = bb;
      sidxR[rc] = myidx;
      cxyR[rc] = make_float2((bb.x + bb.z) * 0.5f, (bb.y + bb.w) * 0.5f);
      areaR[rc] = fence((bb.z - bb.x) * (bb.w - bb.y));
    }
    __syncthreads();  // B: rank-ordered boxes + rmax visible

    // ---- adjacency word h2 of row c2 (wave-aligned; scalar-branch skips) ---
    {
      const int c2 = tid & 255;
      const int h2 = tid >> 8;       // wave-uniform
      const int qbase = h2 << 6;
      if (c2 < cnt) {
        uint64_t acc = 0;
        if (qbase < cnt) {
          float4 mb = candboxR[c2];
          float marea = areaR[c2];
          float mcx = (mb.x + mb.z) * 0.5f;
          float mcy = (mb.y + mb.w) * 0.5f;
          float mrx = (mb.z - mb.x) * 0.5f;
          float mry = (mb.w - mb.y) * 0.5f;
          const float rmaxf = __int_as_float(s_rmax_i);
          // sound overlap bound: real overlap => |dcx| <= mrx + rq <= limx
          // (0.002 absolute guard covers center/extent rounding at |coord|
          //  up to ~2000; prefilter disabled for thr<0 where IoU=0 pairs
          //  could still suppress)
          const float limx = mrx + rmaxf + 0.002f;
          const float limy = mry + rmaxf + 0.002f;
          const bool use_pf = (thr >= 0.0f);
#pragma unroll
          for (int j = 0; j < 64; ++j) {
            const int q = qbase + j;  // wave-uniform -> scalar branch
            if (q < cnt) {
              float2 cq = cxyR[q];
              bool close = (fabsf(cq.x - mcx) <= limx) &
                           (fabsf(cq.y - mcy) <= limy);
              if (!use_pf) close = true;
              if (close) {
                float4 qb = candboxR[q];
                float qarea = areaR[q];
                float iw = fmaxf(fminf(qb.z, mb.z) - fmaxf(qb.x, mb.x), 0.0f);
                float ih = fmaxf(fminf(qb.w, mb.w) - fmaxf(qb.y, mb.y), 0.0f);
                float inter = fence(iw * ih);
                float denom = (qarea + marea) - inter;
                if (inter / denom > thr) acc |= (1ull << j);
              }
            }
          }
        }
        adjm[c2][h2] = acc;  // unconditional: zero unused words (read later)
      }
    }
    __syncthreads();  // C: adjacency visible

    // ---- wave 0: conflict-skip mask greedy (budget-free, truncate after) ---
    if (wid == 0) {
      uint64_t km[4] = {0, 0, 0, 0};
      int kept = 0;
#pragma unroll
      for (int cch = 0; cch < 4; ++cch) {
        if (cch * 64 < cnt && kept < maxout) {
          const int p = cch * 64 + lane;
          const bool valid = p < cnt;
          uint64_t r0 = 0, r1 = 0, r2 = 0, r3 = 0;
          if (valid) {
            r0 = adjm[p][0]; r1 = adjm[p][1];
            r2 = adjm[p][2]; r3 = adjm[p][3];
          }
          const uint64_t self = 1ull << lane;
          bool supp = !valid ||
                      (((r0 & km[0]) | (r1 & km[1]) | (r2 & km[2]) |
                        (r3 & km[3])) != 0);
          uint64_t alive = __ballot(valid && !supp);
          uint64_t wc = (cch == 0) ? r0 : (cch == 1) ? r1 : (cch == 2) ? r2 : r3;
          uint64_t rowNS = wc & ~self;
          uint32_t rlo = (uint32_t)wc, rhi = (uint32_t)(wc >> 32);
          uint64_t keepm = 0;
          // keep-flags are budget-independent (reference truncates after):
          // batch-keep alive bits below the first conflicted bit (its
          // partners are all above it by row symmetry), apply its row, loop.
          while (alive != 0) {
            bool ma = (alive >> lane) & 1;
            uint64_t conf = __ballot(ma && ((rowNS & alive) != 0));
            if (conf == 0) {
              keepm |= alive;
              break;
            }
            int cb = __ffsll((unsigned long long)conf) - 1;
            uint64_t incl = (cb >= 63) ? ~0ull : ((1ull << (cb + 1)) - 1ull);
            keepm |= alive & incl;  // all alive <= cb kept (cb included)
            alive &= ~incl;
            uint64_t rb = ((uint64_t)rdlane32(rhi, cb) << 32) |
                          (uint64_t)rdlane32(rlo, cb);
            alive &= ~rb;  // cb's suppressions
          }
          // budget truncation (exact: keep flags don't depend on budget)
          int nk = __popcll((unsigned long long)keepm);
          const int budget = maxout - kept;
          if (nk > budget) {
            int lo = 0;
#pragma unroll
            for (int s = 32; s >= 1; s >>= 1) {
              int t2 = lo + s;
              uint64_t mk = (t2 >= 64) ? ~0ull : ((1ull << t2) - 1ull);
              if (__popcll((unsigned long long)(keepm & mk)) < budget) lo = t2;
            }
            keepm &= (lo >= 63) ? ~0ull : ((1ull << (lo + 1)) - 1ull);
            nk = budget;
          }
          km[cch] = keepm;
          const int kbase = kept;
          kept += nk;
          if ((keepm >> lane) & 1) {
            int rk = kbase +
                     __popcll((unsigned long long)(keepm & (self - 1ull)));
            kidxS[rk] = sidxR[p];
            float4 pb = candboxR[p];  // keep fallback continuation exact
            kbox[rk] = pb;
            kareaS[rk] = fence((pb.z - pb.x) * (pb.w - pb.y));
          }
        }
      }
      // fast-path output write (overwritten by fallback epilogue if !done)
      for (int i = lane; i < out_size; i += 64)
        out[i] = (i < kept) ? kidxS[i] : -1;
      if (lane == 0) {
        s_kept = kept;
        s_done = (kept >= maxout) ? 1 : 0;
      }
    }
    __syncthreads();  // D
    done = (s_done != 0);
    if (done) return;  // all threads: output already written by wave 0
  }

  {
    // ---- fallback: exact histogram-batched path (not taken on bench) ----
    {
      uint32_t* hh = &hist[0][0];
      for (int i = tid; i < NH * NB; i += THREADS) hh[i] = 0;
    }
    if (tid == 0) {
      s_hi = fast_ok ? 999 : (NB - 1);  // bucket(T0)-1 when fast tier consumed
      if (!fast_ok) s_kept = 0;
      s_done = 0;
    }
    __syncthreads();
    const int hicap = fast_ok ? 999 : (NB - 1);
    {
      uint32_t* myh = hist[wid];
#pragma unroll
      for (int r = 0; r < 8; ++r) {
        if (base + r < n) {
          int b = (int)(sc[r] * (float)NB);
          b = b < 0 ? 0 : (b > NB - 1 ? NB - 1 : b);
          if (b <= hicap) atomicAdd(&myh[b], 1u);
        }
      }
    }
    __syncthreads();
    for (int i = tid; i < NB; i += THREADS) {
      uint32_t s = 0;
#pragma unroll
      for (int hh = 0; hh < NH; ++hh) s += hist[hh][i];
      hist[0][i] = s;
    }
    __syncthreads();

    while (true) {
      if (wid == 0) {
        uint32_t csum = 0;
        const uint4* hp = reinterpret_cast<const uint4*>(&hist[0][lane * 16]);
#pragma unroll
        for (int i = 0; i < 4; ++i) {
          uint4 h4 = hp[i];
          csum += h4.x + h4.y + h4.z + h4.w;
        }
        uint32_t suf = csum;
#pragma unroll
        for (int off = 1; off < 64; off <<= 1) {
          uint32_t v = __shfl_down(suf, off, 64);
          suf += (lane + off < 64) ? v : 0u;
        }
        uint64_t mask = __ballot(suf >= (uint32_t)WANT);
        int cut;
        if (mask == 0) {
          cut = 0;
        } else {
          int cstar = 63 - __builtin_clzll((unsigned long long)mask);
          int src = cstar + 1 < 63 ? cstar + 1 : 63;
          uint32_t above_raw = __shfl(suf, src, 64);
          uint32_t above = (cstar < 63) ? above_raw : 0u;
          uint32_t h2 = (lane < 16) ? hist[0][cstar * 16 + lane] : 0u;
          uint32_t suf2 = h2;
#pragma unroll
          for (int off = 1; off < 64; off <<= 1) {
            uint32_t v = __shfl_down(suf2, off, 64);
            suf2 += (lane + off < 64) ? v : 0u;
          }
          uint64_t mask2 =
              __ballot((lane < 16) && (above + suf2 >= (uint32_t)WANT));
          int b2 = 63 - __builtin_clzll((unsigned long long)mask2);
          cut = cstar * 16 + b2;
        }
        if (lane == 0) s_cut = cut;
      }
      __syncthreads();
      const int cut = s_cut;
      const int hi = s_hi;
      const float lo_f =
          (cut == 0) ? -__builtin_huge_valf() : (float)cut / (float)NB;
      const bool top_open = (hi == NB - 1);
      const float up_f = (float)(hi + 1) / (float)NB;

      int wt = 0;
#pragma unroll
      for (int r = 0; r < 8; ++r) {
        int idx = base + r;
        bool pred = (idx < n) && (sc[r] >= lo_f) && (top_open || sc[r] < up_f);
        wt += __popcll((unsigned long long)__ballot(pred));
      }
      if (lane == 0) wcnt[wid] = (uint32_t)wt;
      __syncthreads();
      int cb2 = 0, tot2 = 0;
#pragma unroll
      for (int w = 0; w < NWAVE; ++w) {
        int cc = (int)wcnt[w];
        if (w < wid) cb2 += cc;
        tot2 += cc;
      }
      {
        int run2 = cb2;
#pragma unroll
        for (int r = 0; r < 8; ++r) {
          int idx = base + r;
          bool pred =
              (idx < n) && (sc[r] >= lo_f) && (top_open || sc[r] < up_f);
          uint64_t m = __ballot(pred);
          if (pred) {
            int pos =
                run2 + __popcll((unsigned long long)(m & ((1ull << lane) - 1)));
            if (pos < CAP) {
              cand[pos] = ((uint64_t)__float_as_uint(sc[r]) << 32) |
                          ((uint64_t)(8192 - idx) << 18) | (uint64_t)pos;
              candbox[pos] =
                  *reinterpret_cast<const float4*>(boxes + 4 * (size_t)idx);
            }
          }
          run2 += __popcll((unsigned long long)m);
        }
      }
      __syncthreads();
      int cnt2 = tot2 > CAP ? CAP : tot2;
      if (wid == 0) {
        uint64_t k2[4];
        sort256(lane, cnt2, cand, k2);
        int kept = greedy4(lane, cnt2, s_kept, maxout, thr, k2, candbox, cbox,
                           careaS, kbox, kareaS, kidxS);
        if (lane == 0) {
          s_kept = kept;
          s_hi = cut - 1;
          s_done = (kept >= maxout || cut == 0) ? 1 : 0;
        }
      }
      __syncthreads();
      if (s_done) break;
      for (int b = cut + tid; b <= hi; b += THREADS) hist[0][b] = 0;
      __syncthreads();
    }
  }

  // fallback epilogue output (harness never re-poisons)
  const int keptf = s_kept;
  for (int i = tid; i < out_size; i += THREADS)
    out[i] = (i < keptf) ? kidxS[i] : -1;
}

extern "C" void kernel_launch(void* const* d_in, const int* in_sizes, int n_in,
                              void* d_out, int out_size, void* d_ws,
                              size_t ws_size, hipStream_t stream) {
  const float* boxes = (const float*)d_in[0];
  const float* scores = (const float*)d_in[1];
  const float* thr = (const float*)d_in[2];
  const int* maxout = (const int*)d_in[3];
  int n = in_sizes[1];
  int* out = (int*)d_out;

  hipLaunchKernelGGL(nms_rank5_kernel, dim3(1), dim3(THREADS), 0, stream,
                     boxes, scores, n, thr, maxout, out, out_size);
}

// Round 10
// 22.984 us; speedup vs baseline: 1.1382x; 1.0117x over previous
//
#include <hip/hip_runtime.h>
#include <stdint.h>

#define THREADS 1024
#define NWAVE 16
#define NB 1024      // fallback histogram buckets over [0,1)
#define NH 16        // per-wave partial histograms
#define CAP 192      // candidate buffer capacity (fast tier)
#define WANT 128     // fallback: target candidates per batch
#define MAXKEEP 128  // kept-list capacity (maxout<=100 on bench)
#define T0 0.982421875f  // 1006/1024, exact float; bucket(T0)=1006 (NB=1024)
#define T0BUCKET 1006

__device__ __forceinline__ float fence(float x) {
  asm("" : "+v"(x));  // block fp-contract; match jnp rounding exactly
  return x;
}

__device__ __forceinline__ uint32_t rdlane32(uint32_t v, int l) {
  return (uint32_t)__builtin_amdgcn_readlane((int)v, l);
}

// ---------------- fallback-only machinery (proven R5-R9) ----------------
#define REGSTAGE(KK, JV)                                              \
  do {                                                                \
    _Pragma("unroll") for (int v = 0; v < 4; ++v) {                   \
      if ((v & (JV)) == 0) {                                          \
        uint64_t a = k[v], b = k[v | (JV)];                           \
        bool descRun = (((v * 64) & (KK)) == 0);                      \
        uint64_t mx = a > b ? a : b, mn = a > b ? b : a;              \
        k[v] = descRun ? mx : mn;                                     \
        k[v | (JV)] = descRun ? mn : mx;                              \
      }                                                               \
    }                                                                 \
  } while (0)

#define SHSTAGE(KK, J)                                                \
  do {                                                                \
    _Pragma("unroll") for (int v = 0; v < 4; ++v) {                   \
      uint64_t a = k[v];                                              \
      uint64_t b = __shfl_xor(a, (J), 64);                            \
      int e = v * 64 + lane;                                          \
      bool descRun = ((e & (KK)) == 0);                               \
      bool lower = ((lane & (J)) == 0);                               \
      uint64_t mx = a > b ? a : b, mn = a > b ? b : a;                \
      k[v] = (descRun == lower) ? mx : mn;                            \
    }                                                                 \
  } while (0)

#define SH32TO1(KK)                                                   \
  SHSTAGE(KK, 32); SHSTAGE(KK, 16); SHSTAGE(KK, 8);                   \
  SHSTAGE(KK, 4); SHSTAGE(KK, 2); SHSTAGE(KK, 1)

__device__ __forceinline__ void sort256(int lane, int cnt,
                                        const uint64_t* cand, uint64_t k[4]) {
#pragma unroll
  for (int v = 0; v < 4; ++v) {
    int e = v * 64 + lane;
    k[v] = (e < cnt) ? cand[e] : 0ull;  // 0 sorts to the end
  }
  SHSTAGE(2, 1);
  SHSTAGE(4, 2); SHSTAGE(4, 1);
  SHSTAGE(8, 4); SHSTAGE(8, 2); SHSTAGE(8, 1);
  SHSTAGE(16, 8); SHSTAGE(16, 4); SHSTAGE(16, 2); SHSTAGE(16, 1);
  SHSTAGE(32, 16); SHSTAGE(32, 8); SHSTAGE(32, 4); SHSTAGE(32, 2);
  SHSTAGE(32, 1);
  SHSTAGE(64, 32); SHSTAGE(64, 16); SHSTAGE(64, 8); SHSTAGE(64, 4);
  SHSTAGE(64, 2); SHSTAGE(64, 1);
  REGSTAGE(128, 1); SH32TO1(128);
  REGSTAGE(256, 2); REGSTAGE(256, 1); SH32TO1(256);
}

__device__ __forceinline__ int greedy4(int lane, int cnt, int kept, int maxout,
                                       float thr, const uint64_t k[4],
                                       const float4* candbox, float4* cbox,
                                       float* careaS, float4* kbox,
                                       float* kareaS, int* kidxS) {
#pragma unroll
  for (int c = 0; c < 4; ++c) {
    if (c * 64 < cnt && kept < maxout) {
      uint64_t key = k[c];
      bool valid = (c * 64 + lane) < cnt;
      int slot = valid ? (int)(key & 0x3FFFF) : 0;
      int idx = valid ? (8192 - (int)((key >> 18) & 0x3FFF)) : 0;
      float4 bb = candbox[slot];
      float x1 = bb.x, y1 = bb.y, x2 = bb.z, y2 = bb.w;
      float areaj = fence((x2 - x1) * (y2 - y1));
      const int kbase = kept;

      bool supp = !valid;
#pragma unroll 4
      for (int t = 0; t < kbase; ++t) {
        float4 kb = kbox[t];
        float ka = kareaS[t];
        float iw = fmaxf(fminf(kb.z, x2) - fmaxf(kb.x, x1), 0.0f);
        float ih = fmaxf(fminf(kb.w, y2) - fmaxf(kb.y, y1), 0.0f);
        float inter = fence(iw * ih);
        float denom = (ka + areaj) - inter;
        if (inter / denom > thr) supp = true;
      }

      cbox[lane] = bb;
      careaS[lane] = areaj;
      uint64_t row = 0;
#pragma unroll 8
      for (int j = 0; j < 64; ++j) {
        float4 ib = cbox[j];
        float ia = careaS[j];
        float iw = fmaxf(fminf(ib.z, x2) - fmaxf(ib.x, x1), 0.0f);
        float ih = fmaxf(fminf(ib.w, y2) - fmaxf(ib.y, y1), 0.0f);
        float inter = fence(iw * ih);
        float denom = (ia + areaj) - inter;
        if (inter / denom > thr) row |= (1ull << j);
      }

      const uint64_t self = 1ull << lane;
      uint64_t alive = __ballot(valid && !supp);
      uint64_t rowNS = row & ~self;
      uint64_t conflict = __ballot(valid && !supp && ((rowNS & alive) != 0));
      uint64_t keepm;
      const int budget = maxout - kept;
      if (conflict == 0) {
        int na = __popcll((unsigned long long)alive);
        if (na <= budget) {
          keepm = alive;
          kept += na;
        } else {
          int lo = 0;
#pragma unroll
          for (int s = 32; s >= 1; s >>= 1) {
            int t2 = lo + s;
            uint64_t mk = (t2 >= 64) ? ~0ull : ((1ull << t2) - 1ull);
            if (__popcll((unsigned long long)(alive & mk)) < budget) lo = t2;
          }
          uint64_t mk2 = ((lo + 1) >= 64) ? ~0ull : ((1ull << (lo + 1)) - 1ull);
          keepm = alive & mk2;
          kept += budget;
        }
      } else {
        uint32_t rlo = (uint32_t)row, rhi = (uint32_t)(row >> 32);
        keepm = 0;
        while (alive != 0 && kept < maxout) {
          int b2 = __ffsll((unsigned long long)alive) - 1;
          keepm |= (1ull << b2);
          kept++;
          uint64_t rb = ((uint64_t)rdlane32(rhi, b2) << 32) |
                        (uint64_t)rdlane32(rlo, b2);
          alive &= ~rb;
          alive &= ~(1ull << b2);
        }
      }
      if ((keepm >> lane) & 1) {
        int rank = __popcll((unsigned long long)(keepm & (self - 1ull)));
        kbox[kbase + rank] = bb;
        kareaS[kbase + rank] = areaj;
        kidxS[kbase + rank] = idx;
      }
    }
  }
  return kept;
}

// ---------------------------------------------------------------------------
__global__ __launch_bounds__(THREADS) void nms_rank6_kernel(
    const float* __restrict__ boxes, const float* __restrict__ scores, int n,
    const float* __restrict__ thr_p, const int* __restrict__ maxout_p,
    int* __restrict__ out, int out_size) {
  __shared__ __align__(16) uint32_t hist[NH][NB];  // 64 KB (fallback only)
  __shared__ uint32_t wcnt[NWAVE];
  __shared__ uint64_t cand[CAP];     // compacted keys (slot order)
  __shared__ float4 candbox[CAP];    // fallback: coords by slot
  __shared__ float4 candboxR[CAP];   // fast: coords by RANK
  __shared__ float2 cxyR[CAP];       // fast: centers by RANK (prefilter)
  __shared__ float areaR[CAP];       // fast: areas by RANK
  __shared__ int sidxR[CAP];         // fast: original index by RANK
  __shared__ uint64_t adjm[CAP][3];  // fast: adjacency rows (rank space)
  __shared__ float4 cbox[64];        // fallback greedy4 scratch
  __shared__ float careaS[64];
  __shared__ float4 kbox[MAXKEEP];
  __shared__ float kareaS[MAXKEEP];
  __shared__ int kidxS[MAXKEEP];
  __shared__ int s_cut, s_hi, s_kept, s_done, s_rmax_i;

  const int tid = threadIdx.x;
  const int lane = tid & 63;
  const int wid = tid >> 6;

  const float thr = *thr_p;
  int maxout = *maxout_p;
  if (maxout > out_size) maxout = out_size;
  if (maxout > MAXKEEP) maxout = MAXKEEP;

  // ---- load this thread's 8 scores into registers (cold HBM, 16-wave TLP) --
  float sc[8];
  const int base = tid * 8;
  if (base + 7 < n) {
    const float4* sp = reinterpret_cast<const float4*>(scores) + 2 * tid;
    float4 a = sp[0], b2 = sp[1];
    sc[0] = a.x; sc[1] = a.y; sc[2] = a.z; sc[3] = a.w;
    sc[4] = b2.x; sc[5] = b2.y; sc[6] = b2.z; sc[7] = b2.w;
  } else {
#pragma unroll
    for (int r = 0; r < 8; ++r)
      sc[r] = (base + r < n) ? scores[base + r] : -1.0f;
  }

  // ---- fast path: count survivors of fixed threshold T0 ----
  int wtot = 0;
#pragma unroll
  for (int r = 0; r < 8; ++r) {
    bool pred = (base + r < n) && (sc[r] >= T0);
    wtot += __popcll((unsigned long long)__ballot(pred));
  }
  if (lane == 0) wcnt[wid] = (uint32_t)wtot;
  if (tid == 0) s_rmax_i = 0;
  __syncthreads();
  int cbase = 0, total = 0;
#pragma unroll
  for (int w = 0; w < NWAVE; ++w) {
    int c = (int)wcnt[w];
    if (w < wid) cbase += c;
    total += c;
  }

  const bool fast_ok = (total <= CAP);  // block-uniform
  bool done = false;
  if (fast_ok) {
    // ---- compact keys (atomic-free, deterministic) + zero-pad ----
    int run = cbase;
#pragma unroll
    for (int r = 0; r < 8; ++r) {
      int idx = base + r;
      bool pred = (idx < n) && (sc[r] >= T0);
      uint64_t m = __ballot(pred);
      if (pred) {
        int pos = run + __popcll((unsigned long long)(m & ((1ull << lane) - 1)));
        // key: [63:32]=score bits, [31:18]=8192-idx (stable tie; >0 so no
        // real key equals the 0 pad), [17:0]=slot (order-neutral).
        cand[pos] = ((uint64_t)__float_as_uint(sc[r]) << 32) |
                    ((uint64_t)(8192 - idx) << 18) | (uint64_t)pos;
      }
      run += __popcll((unsigned long long)m);
    }
    if (tid >= total && tid < CAP) cand[tid] = 0;  // pad sorts last
    __syncthreads();  // A: keys visible

    const int cnt = total;
    const int c = tid >> 2;  // candidate owned by this 4-thread team
    const int h = tid & 3;   // this thread handles cols q == h (mod 4)

    uint64_t mykey = 0;
    float4 bb;
    int myidx = 0;
    if (c < cnt) {
      mykey = cand[c];
      if (h == 0) {  // issue cold box load early; hides under rank loop
        myidx = 8192 - (int)((mykey >> 18) & 0x3FFF);
        bb = *reinterpret_cast<const float4*>(boxes + 4 * (size_t)myidx);
      }
    }

    // ---- rank-by-count: fixed-48 fully-unrolled (pipelined LDS reads) ----
    int rc = 0;
    {
      int r0 = 0, r1 = 0;
#pragma unroll
      for (int i = 0; i < CAP / 8; ++i) {  // two streams: more ILP
        uint64_t ka = cand[8 * i + h];
        uint64_t kb = cand[8 * i + 4 + h];
        r0 += (ka > mykey) ? 1 : 0;
        r1 += (kb > mykey) ? 1 : 0;
      }
      rc = r0 + r1;  // pad keys are 0: never > any real key
    }
    rc += __shfl_xor(rc, 1, 64);
    rc += __shfl_xor(rc, 2, 64);  // all 4 team threads hold full rank

    // block max half-extent (prefilter radius bound; exact upper bound)
    float rm = 0.0f;
    if (c < cnt && h == 0)
      rm = fmaxf((bb.z - bb.x) * 0.5f, (bb.w - bb.y) * 0.5f);
#pragma unroll
    for (int off = 1; off < 64; off <<= 1)
      rm = fmaxf(rm, __shfl_xor(rm, off, 64));
    if (lane == 0) atomicMax(&s_rmax_i, __float_as_int(rm));

    if (c < cnt && h == 0) {
      candboxR[rc] = bb;
      sidxR[rc] = myidx;
      cxyR[rc] = make_float2((bb.x + bb.z) * 0.5f, (bb.y + bb.w) * 0.5f);
      areaR[rc] = fence((bb.z - bb.x) * (bb.w - bb.y));
    }
    __syncthreads();  // B: rank-ordered boxes + rmax visible

    // ---- adjacency word h2 of row c2 (wave-aligned; scalar-branch skips) ---
    {
      const int c2 = tid & 255;
      const int h2 = tid >> 8;  // wave-uniform; words 0..2 used (CAP=192)
      const int qbase = h2 << 6;
      if (c2 < cnt && h2 < 3) {
        uint64_t acc = 0;
        if (qbase < cnt) {
          float4 mb = candboxR[c2];
          float marea = areaR[c2];
          float mcx = (mb.x + mb.z) * 0.5f;
          float mcy = (mb.y + mb.w) * 0.5f;
          float mrx = (mb.z - mb.x) * 0.5f;
          float mry = (mb.w - mb.y) * 0.5f;
          const float rmaxf = __int_as_float(s_rmax_i);
          // sound overlap bound: real overlap => |dcx| <= mrx + rq <= limx
          // (0.002 absolute guard covers center/extent rounding at |coord|
          //  up to ~2000; prefilter disabled for thr<0 where IoU=0 pairs
          //  could still suppress)
          const float limx = mrx + rmaxf + 0.002f;
          const float limy = mry + rmaxf + 0.002f;
          const bool use_pf = (thr >= 0.0f);
#pragma unroll
          for (int j = 0; j < 64; ++j) {
            const int q = qbase + j;  // wave-uniform -> scalar branch
            if (q < cnt) {
              float2 cq = cxyR[q];
              bool close = (fabsf(cq.x - mcx) <= limx) &
                           (fabsf(cq.y - mcy) <= limy);
              if (!use_pf) close = true;
              if (close) {
                float4 qb = candboxR[q];
                float qarea = areaR[q];
                float iw = fmaxf(fminf(qb.z, mb.z) - fmaxf(qb.x, mb.x), 0.0f);
                float ih = fmaxf(fminf(qb.w, mb.w) - fmaxf(qb.y, mb.y), 0.0f);
                float inter = fence(iw * ih);
                float denom = (qarea + marea) - inter;
                if (inter / denom > thr) acc |= (1ull << j);
              }
            }
          }
        }
        adjm[c2][h2] = acc;  // unconditional: zero unused words (read later)
      }
    }
    __syncthreads();  // C: adjacency visible

    // ---- wave 0: conflict-skip mask greedy (budget-free, truncate after) ---
    if (wid == 0) {
      uint64_t km[3] = {0, 0, 0};
      int kept = 0;
#pragma unroll
      for (int cch = 0; cch < 3; ++cch) {
        if (cch * 64 < cnt && kept < maxout) {
          const int p = cch * 64 + lane;
          const bool valid = p < cnt;
          uint64_t r0 = 0, r1 = 0, r2 = 0;
          if (valid) {
            r0 = adjm[p][0]; r1 = adjm[p][1]; r2 = adjm[p][2];
          }
          const uint64_t self = 1ull << lane;
          bool supp = !valid ||
                      (((r0 & km[0]) | (r1 & km[1]) | (r2 & km[2])) != 0);
          uint64_t alive = __ballot(valid && !supp);
          uint64_t wc = (cch == 0) ? r0 : (cch == 1) ? r1 : r2;
          uint64_t rowNS = wc & ~self;
          uint32_t rlo = (uint32_t)wc, rhi = (uint32_t)(wc >> 32);
          uint64_t keepm = 0;
          // keep-flags are budget-independent (reference truncates after):
          // batch-keep alive bits below the first conflicted bit (its
          // partners are all above it by row symmetry), apply its row, loop.
          while (alive != 0) {
            bool ma = (alive >> lane) & 1;
            uint64_t conf = __ballot(ma && ((rowNS & alive) != 0));
            if (conf == 0) {
              keepm |= alive;
              break;
            }
            int cb = __ffsll((unsigned long long)conf) - 1;
            uint64_t incl = (cb >= 63) ? ~0ull : ((1ull << (cb + 1)) - 1ull);
            keepm |= alive & incl;  // all alive <= cb kept (cb included)
            alive &= ~incl;
            uint64_t rb = ((uint64_t)rdlane32(rhi, cb) << 32) |
                          (uint64_t)rdlane32(rlo, cb);
            alive &= ~rb;  // cb's suppressions
          }
          // budget truncation (exact: keep flags don't depend on budget)
          int nk = __popcll((unsigned long long)keepm);
          const int budget = maxout - kept;
          if (nk > budget) {
            int lo = 0;
#pragma unroll
            for (int s = 32; s >= 1; s >>= 1) {
              int t2 = lo + s;
              uint64_t mk = (t2 >= 64) ? ~0ull : ((1ull << t2) - 1ull);
              if (__popcll((unsigned long long)(keepm & mk)) < budget) lo = t2;
            }
            keepm &= (lo >= 63) ? ~0ull : ((1ull << (lo + 1)) - 1ull);
            nk = budget;
          }
          km[cch] = keepm;
          const int kbase = kept;
          kept += nk;
          if ((keepm >> lane) & 1) {
            int rk = kbase +
                     __popcll((unsigned long long)(keepm & (self - 1ull)));
            kidxS[rk] = sidxR[p];
            float4 pb = candboxR[p];  // keep fallback continuation exact
            kbox[rk] = pb;
            kareaS[rk] = fence((pb.z - pb.x) * (pb.w - pb.y));
          }
        }
      }
      // fast-path output write (overwritten by fallback epilogue if !done)
      for (int i = lane; i < out_size; i += 64)
        out[i] = (i < kept) ? kidxS[i] : -1;
      if (lane == 0) {
        s_kept = kept;
        s_done = (kept >= maxout) ? 1 : 0;
      }
    }
    __syncthreads();  // D
    done = (s_done != 0);
    if (done) return;  // all threads: output already written by wave 0
  }

  {
    // ---- fallback: exact histogram-batched path (not taken on bench) ----
    {
      uint32_t* hh = &hist[0][0];
      for (int i = tid; i < NH * NB; i += THREADS) hh[i] = 0;
    }
    if (tid == 0) {
      // fast tier consumed buckets >= bucket(T0) when fast_ok
      s_hi = fast_ok ? (T0BUCKET - 1) : (NB - 1);
      if (!fast_ok) s_kept = 0;
      s_done = 0;
    }
    __syncthreads();
    const int hicap = fast_ok ? (T0BUCKET - 1) : (NB - 1);
    {
      uint32_t* myh = hist[wid];
#pragma unroll
      for (int r = 0; r < 8; ++r) {
        if (base + r < n) {
          int b = (int)(sc[r] * (float)NB);
          b = b < 0 ? 0 : (b > NB - 1 ? NB - 1 : b);
          if (b <= hicap) atomicAdd(&myh[b], 1u);
        }
      }
    }
    __syncthreads();
    for (int i = tid; i < NB; i += THREADS) {
      uint32_t s = 0;
#pragma unroll
      for (int hh = 0; hh < NH; ++hh) s += hist[hh][i];
      hist[0][i] = s;
    }
    __syncthreads();

    while (true) {
      if (wid == 0) {
        uint32_t csum = 0;
        const uint4* hp = reinterpret_cast<const uint4*>(&hist[0][lane * 16]);
#pragma unroll
        for (int i = 0; i < 4; ++i) {
          uint4 h4 = hp[i];
          csum += h4.x + h4.y + h4.z + h4.w;
        }
        uint32_t suf = csum;
#pragma unroll
        for (int off = 1; off < 64; off <<= 1) {
          uint32_t v = __shfl_down(suf, off, 64);
          suf += (lane + off < 64) ? v : 0u;
        }
        uint64_t mask = __ballot(suf >= (uint32_t)WANT);
        int cut;
        if (mask == 0) {
          cut = 0;
        } else {
          int cstar = 63 - __builtin_clzll((unsigned long long)mask);
          int src = cstar + 1 < 63 ? cstar + 1 : 63;
          uint32_t above_raw = __shfl(suf, src, 64);
          uint32_t above = (cstar < 63) ? above_raw : 0u;
          uint32_t h2 = (lane < 16) ? hist[0][cstar * 16 + lane] : 0u;
          uint32_t suf2 = h2;
#pragma unroll
          for (int off = 1; off < 64; off <<= 1) {
            uint32_t v = __shfl_down(suf2, off, 64);
            suf2 += (lane + off < 64) ? v : 0u;
          }
          uint64_t mask2 =
              __ballot((lane < 16) && (above + suf2 >= (uint32_t)WANT));
          int b2 = 63 - __builtin_clzll((unsigned long long)mask2);
          cut = cstar * 16 + b2;
        }
        if (lane == 0) s_cut = cut;
      }
      __syncthreads();
      const int cut = s_cut;
      const int hi = s_hi;
      const float lo_f =
          (cut == 0) ? -__builtin_huge_valf() : (float)cut / (float)NB;
      const bool top_open = (hi == NB - 1);
      const float up_f = (float)(hi + 1) / (float)NB;

      int wt = 0;
#pragma unroll
      for (int r = 0; r < 8; ++r) {
        int idx = base + r;
        bool pred = (idx < n) && (sc[r] >= lo_f) && (top_open || sc[r] < up_f);
        wt += __popcll((unsigned long long)__ballot(pred));
      }
      if (lane == 0) wcnt[wid] = (uint32_t)wt;
      __syncthreads();
      int cb2 = 0, tot2 = 0;
#pragma unroll
      for (int w = 0; w < NWAVE; ++w) {
        int cc = (int)wcnt[w];
        if (w < wid) cb2 += cc;
        tot2 += cc;
      }
      {
        int run2 = cb2;
#pragma unroll
        for (int r = 0; r < 8; ++r) {
          int idx = base + r;
          bool pred =
              (idx < n) && (sc[r] >= lo_f) && (top_open || sc[r] < up_f);
          uint64_t m = __ballot(pred);
          if (pred) {
            int pos =
                run2 + __popcll((unsigned long long)(m & ((1ull << lane) - 1)));
            if (pos < CAP) {
              cand[pos] = ((uint64_t)__float_as_uint(sc[r]) << 32) |
                          ((uint64_t)(8192 - idx) << 18) | (uint64_t)pos;
              candbox[pos] =
                  *reinterpret_cast<const float4*>(boxes + 4 * (size_t)idx);
            }
          }
          run2 += __popcll((unsigned long long)m);
        }
      }
      __syncthreads();
      int cnt2 = tot2 > CAP ? CAP : tot2;
      if (wid == 0) {
        uint64_t k2[4];
        sort256(lane, cnt2, cand, k2);
        int kept = greedy4(lane, cnt2, s_kept, maxout, thr, k2, candbox, cbox,
                           careaS, kbox, kareaS, kidxS);
        if (lane == 0) {
          s_kept = kept;
          s_hi = cut - 1;
          s_done = (kept >= maxout || cut == 0) ? 1 : 0;
        }
      }
      __syncthreads();
      if (s_done) break;
      for (int b = cut + tid; b <= hi; b += THREADS) hist[0][b] = 0;
      __syncthreads();
    }
  }

  // fallback epilogue output (harness never re-poisons)
  const int keptf = s_kept;
  for (int i = tid; i < out_size; i += THREADS)
    out[i] = (i < keptf) ? kidxS[i] : -1;
}

extern "C" void kernel_launch(void* const* d_in, const int* in_sizes, int n_in,
                              void* d_out, int out_size, void* d_ws,
                              size_t ws_size, hipStream_t stream) {
  const float* boxes = (const float*)d_in[0];
  const float* scores = (const float*)d_in[1];
  const float* thr = (const float*)d_in[2];
  const int* maxout = (const int*)d_in[3];
  int n = in_sizes[1];
  int* out = (int*)d_out;

  hipLaunchKernelGGL(nms_rank6_kernel, dim3(1), dim3(THREADS), 0, stream,
                     boxes, scores, n, thr, maxout, out, out_size);
}